// Round 9
// baseline (5410.709 us; speedup 1.0000x reference)
//
#include <hip/hip_runtime.h>
#include <math.h>

// TTT recurrence: one wave (64 lanes) per row, lane = hidden index.
// R7: fast_tanh (exp2+rcp), DPP wave reduction for the head.
// R8: no hot-loop barriers (single wave, DS in-order).
// R11: merged BWD->FWD phases, incremental z1.
// R12: u = w3*(1-h2^2) broadcast (dl factored), fused dot+update loops.
// R13 (reverted): readlane all-gather +29%. R14/R15 (reverted): dual-row
// +34%. R16 (reverted): LDS prefetch +3%. R17/R18 (null): allocator cap
// freed, VGPR stays ~88. R19 (null): forced v_pk_fma_f16 -- already 1 op.
// R20 (this): FULL-F32 HOT LOOP. Wall model (slope-calibrated on R13/R16:
// 4 cyc wall per added instr) says ~480 issue-slots/phase vs ~190 counted:
// ~280 phantom slots pinned to the 128 f16 VOP3P ops. Two surviving
// mechanisms -- (a) VOP3P quarter-rate on gfx950, (b) h2v arrays parked in
// AGPRs (VGPR_Count=80 < the 96 regs the arrays need; accvgpr_read/write
// per access) -- are BOTH cured by going f32: v_fmac_f32 is measured
// full-rate (m07), f32 scalar arrays are first-class for the allocator
// (~170 regs < 256 keeps 2 waves/SIMD). W2 rows+cols in f32 registers;
// h1/u broadcasts stored f32 in LDS; hr[] register array replaced by
// re-reading double-buffered old-h from LDS (DS ops proven non-binding,
// R12). No f16 anywhere in the hot loop; also kills the cvt/pack ops.
// Numerics move CLOSER to the f32 JAX reference (absmax should drop).

#define TT  784
#define HH  64
#define LR  0.01f

// tanh(x) = 1 - 2/(exp2(2*log2e*x)+1); saturates exactly at +-1.
__device__ __forceinline__ float fast_tanh(float x) {
    float e = __builtin_amdgcn_exp2f(x * 2.885390081777926814f);
    float r = __builtin_amdgcn_rcpf(e + 1.0f);
    return fmaf(-2.0f, r, 1.0f);
}

template <int CTRL, int RMASK, bool BC_>
__device__ __forceinline__ float dpp_add(float x) {
    int t = __builtin_amdgcn_update_dpp(0, __builtin_bit_cast(int, x),
                                        CTRL, RMASK, 0xf, BC_);
    return x + __builtin_bit_cast(float, t);
}

// Full wave64 sum -> uniform value (DPP reduce, total in lane 63).
__device__ __forceinline__ float wave_sum(float x) {
    x = dpp_add<0x111, 0xf, true>(x);   // row_shr:1
    x = dpp_add<0x112, 0xf, true>(x);   // row_shr:2
    x = dpp_add<0x114, 0xf, true>(x);   // row_shr:4
    x = dpp_add<0x118, 0xf, true>(x);   // row_shr:8
    x = dpp_add<0x142, 0xa, false>(x);  // row_bcast:15 -> rows 1,3
    x = dpp_add<0x143, 0xc, false>(x);  // row_bcast:31 -> rows 2,3
    return __builtin_bit_cast(float,
        __builtin_amdgcn_readlane(__builtin_bit_cast(int, x), 63));
}

__global__ __launch_bounds__(64, 2)
void ttt_kernel(const float* __restrict__ ts,
                const float* __restrict__ xs,
                const int*   __restrict__ mask,
                const float* __restrict__ W1,
                const float* __restrict__ b1,
                const float* __restrict__ W2,
                const float* __restrict__ b2,
                const float* __restrict__ W3,
                const float* __restrict__ b3,
                float* __restrict__ out)
{
    __shared__ __align__(16) float s_hb[2][HH];  // h1 broadcast, f32, dbuf
    __shared__ __align__(16) float s_ub[HH];     // u = w3*(1-h2^2), f32
    __shared__ float s_ts[TT];
    __shared__ float s_xs[TT];
    __shared__ float s_out[TT];
    __shared__ int   s_mask[TT - 1];

    const int row  = blockIdx.x;
    const int lane = threadIdx.x;  // 0..63

    for (int i = lane; i < TT; i += HH) {
        s_ts[i] = ts[i];
        s_xs[i] = xs[row * TT + i];
    }
    for (int i = lane; i < TT - 1; i += HH) s_mask[i] = mask[row * (TT - 1) + i];

    // Per-lane theta, all f32.
    float w1a = W1[2 * lane + 0];
    float w1b = W1[2 * lane + 1];
    float b1v = b1[lane];
    float b2v = b2[lane];
    float w3v = W3[lane];
    float b3v = b3[0];

    float w2r[HH];  // W2[lane][j]  (row for forward a-dots)
    float w2c[HH];  // W2[j][lane]  (col for backward d-dots)
#pragma unroll
    for (int j = 0; j < HH; ++j) {
        w2r[j] = W2[lane * HH + j];
        w2c[j] = W2[j * HH + lane];
    }
    __syncthreads();  // one-time (staging); outside hot loop

    const float4* hb0 = (const float4*)s_hb[0];  // 16 float4 = 64 f32
    const float4* hb1 = (const float4*)s_hb[1];
    const float4* ub4 = (const float4*)s_ub;

    float t_prev = s_ts[0];
    const float x0 = s_xs[0];
    float x_hat  = x0;
    float x_prev = x0;
    if (lane == 0) s_out[0] = x0;

    float  h1f, h2f, predf;  // own-lane h1, h2; uniform pred
    float  ul;               // own-lane u
    float  z1f;              // current z1 (incremental inside gs loop)
    float  sdz1 = 0.f;       // per-step sum of dz1
    float  tc = 0.f, x_true = 0.f, tin = 0.f, nls = 0.f;

    // Merged phase: BWD of the current pred, then the next forward.
    // hold = f32 LDS buffer holding the h1 that produced predf;
    // hnew/hst = buffer (read-ptr / store-ptr) receiving the new h1.
    auto MERGED = [&](const float4* hold, const float4* hnew, float* hst,
                      float xt, bool final_) {
        // ---- backward scalar head (pure f32, no cvt/pack)
        const float diff = predf - xt;
        const float dl   = diff + diff;
        const float ndl  = -LR * dl;
        w3v = fmaf(ndl, h2f, w3v);       // OLD h2 (this backward's fwd)
        b3v += ndl;
        b2v = fmaf(ndl, ul, b2v);
        const float sd = ndl * ul;       // -LR*dz2s (own lane)
        const float sh = ndl * h1f;      // -LR*dl*h1_old
        // ---- fused: d-dots on OLD w2c + w2c update (one read of u)
        float d0 = 0.f, d1 = 0.f, d2 = 0.f, d3 = 0.f;
#pragma unroll
        for (int k = 0; k < 16; ++k) {
            const float4 q = ub4[k];     // broadcast read (own-wave ordered)
            d0 = fmaf(w2c[4 * k + 0], q.x, d0);
            d1 = fmaf(w2c[4 * k + 1], q.y, d1);
            d2 = fmaf(w2c[4 * k + 2], q.z, d2);
            d3 = fmaf(w2c[4 * k + 3], q.w, d3);
            w2c[4 * k + 0] = fmaf(sh, q.x, w2c[4 * k + 0]);
            w2c[4 * k + 1] = fmaf(sh, q.y, w2c[4 * k + 1]);
            w2c[4 * k + 2] = fmaf(sh, q.z, w2c[4 * k + 2]);
            w2c[4 * k + 3] = fmaf(sh, q.w, w2c[4 * k + 3]);
        }
        const float raw = (d0 + d1) + (d2 + d3);
        const float dh1 = dl * raw;
        const float dz1 = dh1 * fmaf(-h1f, h1f, 1.0f);
        sdz1 += dz1;
        // ---- next forward's z1 (+ materialization on the final phase)
        if (!final_) {
            z1f = fmaf(nls, dz1, z1f);   // exact: inputs fixed over gs loop
        } else {
            w1a = fmaf(-LR * tc,     sdz1, w1a);
            w1b = fmaf(-LR * x_prev, sdz1, w1b);
            b1v = fmaf(-LR,          sdz1, b1v);
            z1f = fmaf(w1a, tin, fmaf(w1b, x_true, b1v));
        }
        h1f = fast_tanh(z1f);
        hst[lane] = h1f;                 // f32 store to the NEW h buffer
        // ---- fused: w2r apply with OLD h (re-read from dbuf LDS) +
        //      forward a-dots with NEW h (in-order after the write)
        float a0 = b2v, a1 = 0.f, a2 = 0.f, a3 = 0.f;
#pragma unroll
        for (int k = 0; k < 16; ++k) {
            const float4 qo = hold[k];   // OLD h1 (previous phase's buffer)
            w2r[4 * k + 0] = fmaf(sd, qo.x, w2r[4 * k + 0]);
            w2r[4 * k + 1] = fmaf(sd, qo.y, w2r[4 * k + 1]);
            w2r[4 * k + 2] = fmaf(sd, qo.z, w2r[4 * k + 2]);
            w2r[4 * k + 3] = fmaf(sd, qo.w, w2r[4 * k + 3]);
            const float4 qn = hnew[k];   // NEW h1 (just written)
            a0 = fmaf(w2r[4 * k + 0], qn.x, a0);
            a1 = fmaf(w2r[4 * k + 1], qn.y, a1);
            a2 = fmaf(w2r[4 * k + 2], qn.z, a2);
            a3 = fmaf(w2r[4 * k + 3], qn.w, a3);
        }
        const float z2 = (a0 + a1) + (a2 + a3);
        h2f = fast_tanh(z2);
        const float uf = w3v * fmaf(-h2f, h2f, 1.0f);
        ul = uf;
        s_ub[lane] = uf;
        predf = wave_sum(w3v * h2f) + b3v;
    };

    // Pre-loop stash: theta0 forward at (ts[1], x0) = t=1's gs0 forward.
    z1f = fmaf(w1a, s_ts[1], fmaf(w1b, x0, b1v));
    h1f = fast_tanh(z1f);
    s_hb[0][lane] = h1f;
    {
        float a0 = b2v, a1 = 0.f, a2 = 0.f, a3 = 0.f;
#pragma unroll
        for (int k = 0; k < 16; ++k) {
            const float4 qn = hb0[k];
            a0 = fmaf(w2r[4 * k + 0], qn.x, a0);
            a1 = fmaf(w2r[4 * k + 1], qn.y, a1);
            a2 = fmaf(w2r[4 * k + 2], qn.z, a2);
            a3 = fmaf(w2r[4 * k + 3], qn.w, a3);
        }
        const float z2 = (a0 + a1) + (a2 + a3);
        h2f = fast_tanh(z2);
        const float uf = w3v * fmaf(-h2f, h2f, 1.0f);
        ul = uf;
        s_ub[lane] = uf;
        predf = wave_sum(w3v * h2f) + b3v;
    }

    for (int t = 1; t < TT; ++t) {
        tc     = s_ts[t];
        x_true = s_xs[t];
        tin    = tc + (tc - t_prev);
        nls    = -LR * fmaf(tc, tc, fmaf(x_prev, x_prev, 1.0f));
        const float x_t = s_mask[t - 1] ? x_true : x_hat;   // teacher forcing

        sdz1 = 0.f;
        // h parity: pre-loop/phase-4 leave current h in buffer 0.
        MERGED(hb0, hb1, s_hb[1], x_t, false);  // BWD gs0 + FWD gs1
        MERGED(hb1, hb0, s_hb[0], x_t, false);  // BWD gs1 + FWD gs2
        MERGED(hb0, hb1, s_hb[1], x_t, false);  // BWD gs2 + FWD gs3
        MERGED(hb1, hb0, s_hb[0], x_t, true);   // BWD gs3 + final forward
        x_hat = predf;

        if (lane == 0) s_out[t] = x_hat;
        t_prev = tc;
        x_prev = x_true;
    }

    // Coalesced flush of the row's outputs (single wave: no barrier needed).
    for (int i = lane; i < TT; i += HH) out[row * TT + i] = s_out[i];
}

extern "C" void kernel_launch(void* const* d_in, const int* in_sizes, int n_in,
                              void* d_out, int out_size, void* d_ws, size_t ws_size,
                              hipStream_t stream) {
    const float* ts   = (const float*)d_in[0];
    const float* xs   = (const float*)d_in[1];
    const int*   mask = (const int*)d_in[2];
    const float* W1   = (const float*)d_in[3];
    const float* b1   = (const float*)d_in[4];
    const float* W2   = (const float*)d_in[5];
    const float* b2   = (const float*)d_in[6];
    const float* W3   = (const float*)d_in[7];
    const float* b3   = (const float*)d_in[8];
    float* out = (float*)d_out;

    const int B = in_sizes[1] / TT;  // 2048
    dim3 grid(B), block(HH);
    hipLaunchKernelGGL(ttt_kernel, grid, block, 0, stream,
                       ts, xs, mask, W1, b1, W2, b2, W3, b3, out);
}